// Round 3
// baseline (279.209 us; speedup 1.0000x reference)
//
#include <hip/hip_runtime.h>
#include <hip/hip_bf16.h>
#include <math.h>
#include <stdint.h>

// ScaleAdaptiveRouter on MI355X (gfx950) — Round 15
// T=16384, H=2048, E=64, K=2112, top-2.
//
// Cross-round model (R12/R13/R14 + m97/m201): every coarse
// one-burst-per-step glds schedule delivers ~13 GB/s per block-pipeline
// (R12 16KB/1.22us, R14 20KB/1.56us, m97 32KB/2.45us) regardless of
// prefetch depth; chip time = steps * set / (13 GB/s * blocks/CU).
// m201's multi-phase counted-vmcnt schedule is the only structure that
// breaks it (47 GB/s single-block). R15 = R12 with the K-step split into
// 2 phases, small glds bursts interleaved with MFMA clusters:
//   ph0: wait vmcnt(5); s_barrier; issue 3 glds (A + B[0:8K] of s+2);
//        split3 + 6 MFMA (nt0) under setprio
//   ph1: wait vmcnt(7); s_barrier; issue 1 glds (B[8K:12K]);
//        6 MFMA (nt1) under setprio
// Per-wave outstanding pinned at 8; 3 LDS slots (48 KB). prep permutes
// B records phase-major: slot(nt) = ((nt&1)<<1)|(nt>>1) so ph0 consumes
// records 0-5 (nt0 of both g) and ph1 records 6-11. Compute, numerics,
// epilogue identical to R12 (bit-identical logits).

#define H_DIM 2048
#define K_TOTAL 2112
#define E_DIM 64
#define SE_DIM 64
#define NSTEP 64                        // K32 steps over H
#define TPB 32                          // tokens per block
#define NBLOCKS (16384 / TPB)           // 512 -> 2 blocks/CU
#define STEP_BYTES (12 * 1024)          // 12 B-records of 1 KB per step
#define SET_BYTES (16 * 1024)           // A 4KB + B 12KB
#define WP_TOTAL (NSTEP * STEP_BYTES)   // 786432 B
#define MINS(v) ((v) < NSTEP ? (v) : (NSTEP - 1))

typedef float  f32x4 __attribute__((ext_vector_type(4)));
typedef short  s16x8 __attribute__((ext_vector_type(8)));
typedef unsigned int u32x4 __attribute__((ext_vector_type(4)));

typedef uint32_t __attribute__((address_space(1))) gu32_t;
typedef uint32_t __attribute__((address_space(3))) lu32_t;
__device__ __forceinline__ void gload_lds16(const void* g, void* l) {
    __builtin_amdgcn_global_load_lds((const gu32_t*)g, (lu32_t*)l, 16, 0, 0);
}

__device__ __forceinline__ unsigned short bf16_rne(float f) {
    uint32_t u = __float_as_uint(f);
    return (unsigned short)((u + 0x7FFFu + ((u >> 16) & 1u)) >> 16);
}
__device__ __forceinline__ float bf16_f32(unsigned short h) {
    return __uint_as_float(((uint32_t)h) << 16);
}
__device__ __forceinline__ uint32_t bits_of_bf2(__hip_bfloat162 h) {
    uint32_t u; __builtin_memcpy(&u, &h, 4); return u;
}

// ---- prep: split W into 3 bf16 planes laid out as MFMA B-fragments ----
// B-frag (16x16x32): lane l -> n = l&15, k = (l>>4)*8 + j. Record 1 KB.
// Phase-major record order within a step: slot(nt) = ((nt&1)<<1)|(nt>>1)
//   nt0(e0-15)->0, nt2(e32-47)->1, nt1(e16-31)->2, nt3(e48-63)->3
// rec index = s*12 + slot*3 + p.  [fragment layout R6-verified]
__global__ void prep_kernel(const float* __restrict__ W,
                            const float* __restrict__ se,
                            const int* __restrict__ sidx,
                            unsigned short* __restrict__ Wp,
                            float* __restrict__ tail) {
    if (blockIdx.x == 64) {
        int e = threadIdx.x;
        if (e < 64) {
            const float* emb = se + (*sidx) * SE_DIM;
            float t = 0.f;
            for (int j = 0; j < SE_DIM; ++j)
                t = fmaf(emb[j], W[(size_t)e * K_TOTAL + H_DIM + j], t);
            tail[e] = t;
        }
        return;
    }
    int item = blockIdx.x * 256 + threadIdx.x;   // (s, nt, lane)
    int lane = item & 63;
    int nt   = (item >> 6) & 3;
    int s    = item >> 8;
    int e     = nt * 16 + (lane & 15);
    int kbase = s * 32 + (lane >> 4) * 8;
    const float* wr = W + (size_t)e * K_TOTAL + kbase;
    unsigned short p0[8], p1[8], p2[8];
    #pragma unroll
    for (int j = 0; j < 8; ++j) {
        float v = wr[j];
        unsigned short a0 = bf16_rne(v);
        float r1 = v - bf16_f32(a0);
        unsigned short a1 = bf16_rne(r1);
        float r2 = r1 - bf16_f32(a1);
        p0[j] = a0; p1[j] = a1; p2[j] = bf16_rne(r2);
    }
    int slot = ((nt & 1) << 1) | (nt >> 1);      // phase-major permutation
    size_t rec = (size_t)s * 12 + slot * 3;
    unsigned short* d0 = Wp + (rec + 0) * 512 + lane * 8;
    unsigned short* d1 = Wp + (rec + 1) * 512 + lane * 8;
    unsigned short* d2 = Wp + (rec + 2) * 512 + lane * 8;
    #pragma unroll
    for (int j = 0; j < 8; ++j) { d0[j] = p0[j]; d1[j] = p1[j]; d2[j] = p2[j]; }
}

// split 8 consecutive-k floats into 3 bf16 A-fragment planes (packed pairs)
__device__ __forceinline__ void split3(const float4 fa, const float4 fb,
                                       s16x8& P0, s16x8& P1, s16x8& P2) {
    float f[8] = {fa.x, fa.y, fa.z, fa.w, fb.x, fb.y, fb.z, fb.w};
    uint32_t d0[4], d1[4], d2[4];
    #pragma unroll
    for (int p = 0; p < 4; ++p) {
        float v0 = f[2 * p], v1 = f[2 * p + 1];
        uint32_t u0 = bits_of_bf2(__float22bfloat162_rn(make_float2(v0, v1)));
        float r0 = v0 - __uint_as_float(u0 << 16);
        float r1 = v1 - __uint_as_float(u0 & 0xffff0000u);
        uint32_t u1 = bits_of_bf2(__float22bfloat162_rn(make_float2(r0, r1)));
        float s0 = r0 - __uint_as_float(u1 << 16);
        float s1 = r1 - __uint_as_float(u1 & 0xffff0000u);
        uint32_t u2 = bits_of_bf2(__float22bfloat162_rn(make_float2(s0, s1)));
        d0[p] = u0; d1[p] = u1; d2[p] = u2;
    }
    u32x4 q0 = {d0[0], d0[1], d0[2], d0[3]};
    u32x4 q1 = {d1[0], d1[1], d1[2], d1[3]};
    u32x4 q2 = {d2[0], d2[1], d2[2], d2[3]};
    __builtin_memcpy(&P0, &q0, 16);
    __builtin_memcpy(&P1, &q1, 16);
    __builtin_memcpy(&P2, &q2, 16);
}

__launch_bounds__(256, 2)
__global__ void router_kernel(const float* __restrict__ x,
                              const unsigned char* __restrict__ Wp,
                              const float* __restrict__ tail_g,
                              const float* __restrict__ noise,
                              float* __restrict__ out) {
    __shared__ __align__(16) unsigned char S[3][SET_BYTES];  // 48 KB slots
    __shared__ float4 cand2[2][TPB];                         // 1 KB
    __shared__ float4 res[TPB];                              // 0.5 KB

    const int tid  = threadIdx.x;
    const int lane = tid & 63;
    const int wave = __builtin_amdgcn_readfirstlane(tid >> 6);
    const int mt   = wave >> 1;         // m-tile 0/1 (16 tokens each)
    const int g    = wave & 1;          // expert group: experts g*32 .. g*32+31
    const int tok0 = blockIdx.x * TPB;
    const int row  = lane & 15;         // token within m-tile
    const int quad = lane >> 4;         // k-quad
    const int c    = row;               // expert col within 16-slice

    // ---- staging (thread t): ph0 = {A chunk t, B chunks t, t+256};
    //      ph1 = {B chunk t+512}. Slot layout: [A 4KB | B 12KB].
    // A chunk: stok = t>>3, spos = t&7, src granule spos^(stok&7) (XOR
    // swizzle folded into global src; glds dst lane-linear, m104).
    const int stok = tid >> 3;
    const int spos = tid & 7;
    const int schk = spos ^ (stok & 7);
    const float* asrc = x + (size_t)(tok0 + stok) * H_DIM + schk * 4;
    const unsigned char* bsrc = Wp + (size_t)tid * 16;

    // A fragment read offsets: token mt*16+row, chunks 2q,2q+1 (deswizzled)
    const int abase = (mt * 16 + row) * 128;
    const int aoff0 = abase + (((quad * 2)     ^ (row & 7)) << 4);
    const int aoff1 = abase + (((quad * 2 + 1) ^ (row & 7)) << 4);

    f32x4 acc0 = {0.f, 0.f, 0.f, 0.f}, acc1 = acc0;

    #define ISSUE_P0(s_, d_) do {                                       \
        const unsigned char* _b = bsrc + (size_t)(s_) * STEP_BYTES;     \
        gload_lds16(asrc + (size_t)(s_) * 32, &S[d_][tid * 16]);        \
        gload_lds16(_b,        &S[d_][4096 + tid * 16]);                \
        gload_lds16(_b + 4096, &S[d_][8192 + tid * 16]);                \
    } while (0)
    #define ISSUE_P1(s_, d_)                                            \
        gload_lds16(bsrc + (size_t)(s_) * STEP_BYTES + 8192,            \
                    &S[d_][12288 + tid * 16])

    // ---- prologue: sets 0,1 grouped [3,1,3,1] -> 8 outstanding ----
    ISSUE_P0(0, 0); ISSUE_P1(0, 0);
    ISSUE_P0(1, 1); ISSUE_P1(1, 1);

    int rd = 0, wr = 2;                  // read slot s%3, write slot (s+2)%3
    for (int s = 0; s < NSTEP; ++s) {
        // ---- phase 0: drain set-s ph0 burst (oldest 3) ----
        asm volatile("s_waitcnt vmcnt(5)\n\ts_barrier" ::: "memory");
        // slot wr last read at step s-1; all waves past that via barrier
        ISSUE_P0(MINS(s + 2), wr);

        const unsigned char* sb = &S[rd][0];
        float4 a0 = *(const float4*)(sb + aoff0);
        float4 a1 = *(const float4*)(sb + aoff1);
        s16x8 A0, A1, A2;
        split3(a0, a1, A0, A1, A2);
        {
            const unsigned char* bb = sb + 4096 + g * 3072 + lane * 16;
            s16x8 B0 = *(const s16x8*)(bb);
            s16x8 B1 = *(const s16x8*)(bb + 1024);
            s16x8 B2 = *(const s16x8*)(bb + 2048);
            __builtin_amdgcn_s_setprio(1);
            acc0 = __builtin_amdgcn_mfma_f32_16x16x32_bf16(A0, B0, acc0, 0, 0, 0);
            acc0 = __builtin_amdgcn_mfma_f32_16x16x32_bf16(A0, B1, acc0, 0, 0, 0);
            acc0 = __builtin_amdgcn_mfma_f32_16x16x32_bf16(A1, B0, acc0, 0, 0, 0);
            acc0 = __builtin_amdgcn_mfma_f32_16x16x32_bf16(A0, B2, acc0, 0, 0, 0);
            acc0 = __builtin_amdgcn_mfma_f32_16x16x32_bf16(A1, B1, acc0, 0, 0, 0);
            acc0 = __builtin_amdgcn_mfma_f32_16x16x32_bf16(A2, B0, acc0, 0, 0, 0);
            __builtin_amdgcn_s_setprio(0);
        }

        // ---- phase 1: drain set-s ph1 chunk (oldest 1) ----
        asm volatile("s_waitcnt vmcnt(7)\n\ts_barrier" ::: "memory");
        ISSUE_P1(MINS(s + 2), wr);
        {
            const unsigned char* bb = sb + 10240 + g * 3072 + lane * 16;
            s16x8 B0 = *(const s16x8*)(bb);
            s16x8 B1 = *(const s16x8*)(bb + 1024);
            s16x8 B2 = *(const s16x8*)(bb + 2048);
            __builtin_amdgcn_s_setprio(1);
            acc1 = __builtin_amdgcn_mfma_f32_16x16x32_bf16(A0, B0, acc1, 0, 0, 0);
            acc1 = __builtin_amdgcn_mfma_f32_16x16x32_bf16(A0, B1, acc1, 0, 0, 0);
            acc1 = __builtin_amdgcn_mfma_f32_16x16x32_bf16(A1, B0, acc1, 0, 0, 0);
            acc1 = __builtin_amdgcn_mfma_f32_16x16x32_bf16(A0, B2, acc1, 0, 0, 0);
            acc1 = __builtin_amdgcn_mfma_f32_16x16x32_bf16(A1, B1, acc1, 0, 0, 0);
            acc1 = __builtin_amdgcn_mfma_f32_16x16x32_bf16(A2, B0, acc1, 0, 0, 0);
            __builtin_amdgcn_s_setprio(0);
        }

        rd = (rd == 2) ? 0 : rd + 1;
        wr = (wr == 2) ? 0 : wr + 1;
    }
    #undef ISSUE_P0
    #undef ISSUE_P1

    // ---- epilogue: tail + noise, top-2 over this wave's 32 experts ----
    // C/D: col = lane&15 -> expert g*32 + nt*16 + c; row = quad*4 + r
    float tl0 = tail_g[g * 32 + c], tl1 = tail_g[g * 32 + 16 + c];
    #pragma unroll
    for (int r = 0; r < 4; ++r) {
        const int tl = mt * 16 + quad * 4 + r;              // block-local token
        const float* nz = noise + (size_t)(tok0 + tl) * E_DIM + g * 32;
        float v0 = acc0[r] + tl0 + 0.1f * nz[c];
        float v1 = acc1[r] + tl1 + 0.1f * nz[16 + c];
        // per-lane top-2 (v0's index < v1's index -> ties keep v0)
        float V1, V2; int I1, I2;
        if (v1 > v0) { V1 = v1; I1 = g * 32 + 16 + c; V2 = v0; I2 = g * 32 + c; }
        else         { V1 = v0; I1 = g * 32 + c;      V2 = v1; I2 = g * 32 + 16 + c; }
        // butterfly over the 16 lanes of this quad group
        #pragma unroll
        for (int m = 8; m; m >>= 1) {
            float o1 = __shfl_xor(V1, m, 64); int oi1 = __shfl_xor(I1, m, 64);
            float o2 = __shfl_xor(V2, m, 64); int oi2 = __shfl_xor(I2, m, 64);
            if (o1 > V1 || (o1 == V1 && oi1 < I1)) {
                float nv2; int ni2;
                if (V1 > o2 || (V1 == o2 && I1 < oi2)) { nv2 = V1; ni2 = I1; }
                else                                   { nv2 = o2; ni2 = oi2; }
                V1 = o1; I1 = oi1; V2 = nv2; I2 = ni2;
            } else {
                if (o1 > V2 || (o1 == V2 && oi1 < I2)) { V2 = o1; I2 = oi1; }
            }
        }
        if (c == r)
            cand2[g][tl] = make_float4(V1, __int_as_float(I1), V2, __int_as_float(I2));
    }
    __syncthreads();

    // ---- merge the two 32-expert groups per token (disjoint ranges) ----
    if (tid < TPB) {
        float4 q0 = cand2[0][tid];                  // experts 0..31 (lower idx)
        float4 q1 = cand2[1][tid];                  // experts 32..63
        float V1 = q0.x, V2 = q0.z;
        int   I1 = __float_as_int(q0.y), I2 = __float_as_int(q0.w);
        if (q1.x > V1) {                            // strict: q0 wins ties
            if (q1.z > V1) { V2 = q1.z; I2 = __float_as_int(q1.w); }
            else           { V2 = V1;   I2 = I1; }
            V1 = q1.x; I1 = __float_as_int(q1.y);
        } else if (q1.x > V2) {
            V2 = q1.x; I2 = __float_as_int(q1.y);
        }
        float d   = expf(V2 - V1);                  // softmax denom cancels
        float inv = 1.0f / (1.0f + d);
        res[tid] = make_float4(inv, __int_as_float(I1), d * inv, __int_as_float(I2));
    }
    __syncthreads();

    // ---- composed coalesced store: 32 tokens x 64 experts ----
    float4* outb = (float4*)out + (size_t)blockIdx.x * (TPB * E_DIM / 4);
    #pragma unroll
    for (int pp = 0; pp < 2; ++pp) {
        int p = tid + pp * 256;                     // 0..511
        int t = p >> 4, cc = p & 15;
        float4 rr = res[t];
        int ri1 = __float_as_int(rr.y), ri2 = __float_as_int(rr.w);
        int e = cc * 4;
        float4 o;
        o.x = (e + 0 == ri1) ? rr.x : (e + 0 == ri2) ? rr.z : 0.0f;
        o.y = (e + 1 == ri1) ? rr.x : (e + 1 == ri2) ? rr.z : 0.0f;
        o.z = (e + 2 == ri1) ? rr.x : (e + 2 == ri2) ? rr.z : 0.0f;
        o.w = (e + 3 == ri1) ? rr.x : (e + 3 == ri2) ? rr.z : 0.0f;
        outb[p] = o;
    }
}

extern "C" void kernel_launch(void* const* d_in, const int* in_sizes, int n_in,
                              void* d_out, int out_size, void* d_ws, size_t ws_size,
                              hipStream_t stream) {
    const float* x     = (const float*)d_in[0];
    const float* se    = (const float*)d_in[1];
    const float* W     = (const float*)d_in[2];
    const float* noise = (const float*)d_in[3];
    const int*   sidx  = (const int*)d_in[4];
    float* out = (float*)d_out;

    unsigned short* Wp   = (unsigned short*)d_ws;                 // 786432 B
    float*          tail = (float*)((char*)d_ws + WP_TOTAL);      // 256 B

    hipLaunchKernelGGL(prep_kernel, dim3(65), dim3(256), 0, stream, W, se, sidx, Wp, tail);
    hipLaunchKernelGGL(router_kernel, dim3(NBLOCKS), dim3(256), 0, stream,
                       x, (const unsigned char*)Wp, tail, noise, out);
}

// Round 5
// 252.117 us; speedup vs baseline: 1.1075x; 1.1075x over previous
//
#include <hip/hip_runtime.h>
#include <hip/hip_bf16.h>
#include <math.h>
#include <stdint.h>

// ScaleAdaptiveRouter on MI355X (gfx950) — Round 16 (resubmit; R4 bench was
// an infra failure: "MI355X container failed twice", no counters produced)
// T=16384, H=2048, E=64, K=2112, top-2.
//
// R12-R15 post-mortem: every glds+barrier schedule (coarse, 8-wave,
// TPB=64, 2-phase) lands at 78-131us with NO pipe saturated (HBM 9%,
// MFMA <13%, VALU <26%, L2 well under ceiling). Residual suspect: the
// block-wide barrier+vmcnt drain couples all waves to the slowest
// in-flight glds, and the in-order glds queue makes one HBM-latency
// A-load gate the L2-hit B-loads behind it.
// R16 removes the coupling: NO LDS, NO barriers, NO glds in the K-loop.
// Wp is stored in fragment order, so one B-record = one perfectly
// coalesced global_load_dwordx4 (1 KB/wave-instr) DIRECT TO VGPRs.
// A-fragments load direct too (a0 pulls full 128B lines, a1 L1-hits).
//   - 256 blocks x 512 thr, TPB=64; 8 independent waves = (mt0-3)x(g0-1),
//     each: 16 tokens x 32 experts, 2 A-loads + 6 B-loads + split3 +
//     bit-identical R6 6-term MFMA chain per step. Waves never sync
//     until the epilogue.
//   - depth-2 register pipeline, hand-rotated named frags (static
//     indexing), unroll-2 body; compiler emits counted vmcnt waits.
//   - B dedup x4 / A dedup x2 served by L1 -> unique L2 traffic
//     20 KB/CU/step.
// Logits bit-identical to R12 (same A/B bits, same MFMA order) ->
// absmax must stay exactly 0.00390625.

#define H_DIM 2048
#define K_TOTAL 2112
#define E_DIM 64
#define SE_DIM 64
#define NSTEP 64                        // K32 steps over H
#define TPB 64                          // tokens per block
#define NBLOCKS (16384 / TPB)           // 256
#define STEP_BYTES (12 * 1024)          // 12 B-records of 1 KB per step
#define WP_TOTAL (NSTEP * STEP_BYTES)   // 786432 B
#define MINS(v) ((v) < NSTEP ? (v) : (NSTEP - 1))

typedef float  f32x4 __attribute__((ext_vector_type(4)));
typedef short  s16x8 __attribute__((ext_vector_type(8)));
typedef unsigned int u32x4 __attribute__((ext_vector_type(4)));

__device__ __forceinline__ unsigned short bf16_rne(float f) {
    uint32_t u = __float_as_uint(f);
    return (unsigned short)((u + 0x7FFFu + ((u >> 16) & 1u)) >> 16);
}
__device__ __forceinline__ float bf16_f32(unsigned short h) {
    return __uint_as_float(((uint32_t)h) << 16);
}
__device__ __forceinline__ uint32_t bits_of_bf2(__hip_bfloat162 h) {
    uint32_t u; __builtin_memcpy(&u, &h, 4); return u;
}

// ---- prep: split W into 3 bf16 planes laid out as MFMA B-fragments ----
// B-frag (16x16x32): lane l -> n = l&15, k = (l>>4)*8 + j. Record (s,nt,p):
// 64 lanes x 8 bf16 = 1 KB; record index = s*12 + nt*3 + p.  [R6-verified]
__global__ void prep_kernel(const float* __restrict__ W,
                            const float* __restrict__ se,
                            const int* __restrict__ sidx,
                            unsigned short* __restrict__ Wp,
                            float* __restrict__ tail) {
    if (blockIdx.x == 64) {
        int e = threadIdx.x;
        if (e < 64) {
            const float* emb = se + (*sidx) * SE_DIM;
            float t = 0.f;
            for (int j = 0; j < SE_DIM; ++j)
                t = fmaf(emb[j], W[(size_t)e * K_TOTAL + H_DIM + j], t);
            tail[e] = t;
        }
        return;
    }
    int item = blockIdx.x * 256 + threadIdx.x;   // (s, nt, lane)
    int lane = item & 63;
    int nt   = (item >> 6) & 3;
    int s    = item >> 8;
    int e     = nt * 16 + (lane & 15);
    int kbase = s * 32 + (lane >> 4) * 8;
    const float* wr = W + (size_t)e * K_TOTAL + kbase;
    unsigned short p0[8], p1[8], p2[8];
    #pragma unroll
    for (int j = 0; j < 8; ++j) {
        float v = wr[j];
        unsigned short a0 = bf16_rne(v);
        float r1 = v - bf16_f32(a0);
        unsigned short a1 = bf16_rne(r1);
        float r2 = r1 - bf16_f32(a1);
        p0[j] = a0; p1[j] = a1; p2[j] = bf16_rne(r2);
    }
    size_t rec = (size_t)s * 12 + nt * 3;
    unsigned short* d0 = Wp + (rec + 0) * 512 + lane * 8;
    unsigned short* d1 = Wp + (rec + 1) * 512 + lane * 8;
    unsigned short* d2 = Wp + (rec + 2) * 512 + lane * 8;
    #pragma unroll
    for (int j = 0; j < 8; ++j) { d0[j] = p0[j]; d1[j] = p1[j]; d2[j] = p2[j]; }
}

// split 8 consecutive-k floats into 3 bf16 A-fragment planes (packed pairs)
__device__ __forceinline__ void split3(const float4 fa, const float4 fb,
                                       s16x8& P0, s16x8& P1, s16x8& P2) {
    float f[8] = {fa.x, fa.y, fa.z, fa.w, fb.x, fb.y, fb.z, fb.w};
    uint32_t d0[4], d1[4], d2[4];
    #pragma unroll
    for (int p = 0; p < 4; ++p) {
        float v0 = f[2 * p], v1 = f[2 * p + 1];
        uint32_t u0 = bits_of_bf2(__float22bfloat162_rn(make_float2(v0, v1)));
        float r0 = v0 - __uint_as_float(u0 << 16);
        float r1 = v1 - __uint_as_float(u0 & 0xffff0000u);
        uint32_t u1 = bits_of_bf2(__float22bfloat162_rn(make_float2(r0, r1)));
        float s0 = r0 - __uint_as_float(u1 << 16);
        float s1 = r1 - __uint_as_float(u1 & 0xffff0000u);
        uint32_t u2 = bits_of_bf2(__float22bfloat162_rn(make_float2(s0, s1)));
        d0[p] = u0; d1[p] = u1; d2[p] = u2;
    }
    u32x4 q0 = {d0[0], d0[1], d0[2], d0[3]};
    u32x4 q1 = {d1[0], d1[1], d1[2], d1[3]};
    u32x4 q2 = {d2[0], d2[1], d2[2], d2[3]};
    __builtin_memcpy(&P0, &q0, 16);
    __builtin_memcpy(&P1, &q1, 16);
    __builtin_memcpy(&P2, &q2, 16);
}

// one step's register-resident operand set (per wave)
struct Frag {
    float4 a0, a1;
    s16x8  b0, b1, b2, b3, b4, b5;
};

__device__ __forceinline__ void load_set(const float* ap,
                                         const unsigned char* bp, Frag& f) {
    f.a0 = *(const float4*)(ap);
    f.a1 = *(const float4*)(ap + 4);
    f.b0 = *(const s16x8*)(bp);
    f.b1 = *(const s16x8*)(bp + 1024);
    f.b2 = *(const s16x8*)(bp + 2048);
    f.b3 = *(const s16x8*)(bp + 3072);
    f.b4 = *(const s16x8*)(bp + 4096);
    f.b5 = *(const s16x8*)(bp + 5120);
}

__device__ __forceinline__ void step_compute(const Frag& f,
                                             f32x4& acc0, f32x4& acc1) {
    s16x8 A0, A1, A2;
    split3(f.a0, f.a1, A0, A1, A2);
    // nt0 (b0..b2) then nt1 (b3..b5), R6-verified 6-term order each
    acc0 = __builtin_amdgcn_mfma_f32_16x16x32_bf16(A0, f.b0, acc0, 0, 0, 0);
    acc0 = __builtin_amdgcn_mfma_f32_16x16x32_bf16(A0, f.b1, acc0, 0, 0, 0);
    acc0 = __builtin_amdgcn_mfma_f32_16x16x32_bf16(A1, f.b0, acc0, 0, 0, 0);
    acc0 = __builtin_amdgcn_mfma_f32_16x16x32_bf16(A0, f.b2, acc0, 0, 0, 0);
    acc0 = __builtin_amdgcn_mfma_f32_16x16x32_bf16(A1, f.b1, acc0, 0, 0, 0);
    acc0 = __builtin_amdgcn_mfma_f32_16x16x32_bf16(A2, f.b0, acc0, 0, 0, 0);
    acc1 = __builtin_amdgcn_mfma_f32_16x16x32_bf16(A0, f.b3, acc1, 0, 0, 0);
    acc1 = __builtin_amdgcn_mfma_f32_16x16x32_bf16(A0, f.b4, acc1, 0, 0, 0);
    acc1 = __builtin_amdgcn_mfma_f32_16x16x32_bf16(A1, f.b3, acc1, 0, 0, 0);
    acc1 = __builtin_amdgcn_mfma_f32_16x16x32_bf16(A0, f.b5, acc1, 0, 0, 0);
    acc1 = __builtin_amdgcn_mfma_f32_16x16x32_bf16(A1, f.b4, acc1, 0, 0, 0);
    acc1 = __builtin_amdgcn_mfma_f32_16x16x32_bf16(A2, f.b3, acc1, 0, 0, 0);
}

__launch_bounds__(512, 2)
__global__ void router_kernel(const float* __restrict__ x,
                              const unsigned char* __restrict__ Wp,
                              const float* __restrict__ tail_g,
                              const float* __restrict__ noise,
                              float* __restrict__ out) {
    __shared__ float4 cand2[2][TPB];                         // 2 KB
    __shared__ float4 res[TPB];                              // 1 KB

    const int tid  = threadIdx.x;                    // 0..511
    const int lane = tid & 63;
    const int wave = __builtin_amdgcn_readfirstlane(tid >> 6);  // 0..7
    const int mt   = wave >> 1;         // m-tile 0..3 (16 tokens each)
    const int g    = wave & 1;          // expert group: experts g*32..g*32+31
    const int tok0 = blockIdx.x * TPB;
    const int row  = lane & 15;         // token within m-tile
    const int quad = lane >> 4;         // k-quad
    const int c    = row;               // expert col within 16-slice

    // per-lane operand pointers (A: token row, k floats s*32+quad*8..+8;
    // B: record (s*12 + g*6 + r), lane slice l*16)
    const float* ap = x + (size_t)(tok0 + mt * 16 + row) * H_DIM + quad * 8;
    const unsigned char* bp = Wp + (size_t)g * 6144 + lane * 16;

    f32x4 acc0 = {0.f, 0.f, 0.f, 0.f}, acc1 = acc0;

    // ---- K loop: depth-2 register pipeline, zero barriers ----
    Frag f0, f1;
    load_set(ap, bp, f0);
    #pragma unroll 1
    for (int s = 0; s < NSTEP; s += 2) {
        load_set(ap + (size_t)(s + 1) * 32,
                 bp + (size_t)(s + 1) * STEP_BYTES, f1);
        step_compute(f0, acc0, acc1);
        const int s2 = MINS(s + 2);
        load_set(ap + (size_t)s2 * 32,
                 bp + (size_t)s2 * STEP_BYTES, f0);
        step_compute(f1, acc0, acc1);
    }

    // ---- epilogue: tail + noise, top-2 over this wave's 32 experts ----
    // C/D: col = lane&15 -> expert g*32 + nt*16 + c; row = quad*4 + r
    float tl0 = tail_g[g * 32 + c], tl1 = tail_g[g * 32 + 16 + c];
    #pragma unroll
    for (int r = 0; r < 4; ++r) {
        const int tl = mt * 16 + quad * 4 + r;              // block-local token
        const float* nz = noise + (size_t)(tok0 + tl) * E_DIM + g * 32;
        float v0 = acc0[r] + tl0 + 0.1f * nz[c];
        float v1 = acc1[r] + tl1 + 0.1f * nz[16 + c];
        // per-lane top-2 (v0's index < v1's index -> ties keep v0)
        float V1, V2; int I1, I2;
        if (v1 > v0) { V1 = v1; I1 = g * 32 + 16 + c; V2 = v0; I2 = g * 32 + c; }
        else         { V1 = v0; I1 = g * 32 + c;      V2 = v1; I2 = g * 32 + 16 + c; }
        // butterfly over the 16 lanes of this quad group
        #pragma unroll
        for (int m = 8; m; m >>= 1) {
            float o1 = __shfl_xor(V1, m, 64); int oi1 = __shfl_xor(I1, m, 64);
            float o2 = __shfl_xor(V2, m, 64); int oi2 = __shfl_xor(I2, m, 64);
            if (o1 > V1 || (o1 == V1 && oi1 < I1)) {
                float nv2; int ni2;
                if (V1 > o2 || (V1 == o2 && I1 < oi2)) { nv2 = V1; ni2 = I1; }
                else                                   { nv2 = o2; ni2 = oi2; }
                V1 = o1; I1 = oi1; V2 = nv2; I2 = ni2;
            } else {
                if (o1 > V2 || (o1 == V2 && oi1 < I2)) { V2 = o1; I2 = oi1; }
            }
        }
        if (c == r)
            cand2[g][tl] = make_float4(V1, __int_as_float(I1), V2, __int_as_float(I2));
    }
    __syncthreads();

    // ---- merge the two 32-expert groups per token (disjoint ranges) ----
    if (tid < TPB) {
        float4 q0 = cand2[0][tid];                  // experts 0..31 (lower idx)
        float4 q1 = cand2[1][tid];                  // experts 32..63
        float V1 = q0.x, V2 = q0.z;
        int   I1 = __float_as_int(q0.y), I2 = __float_as_int(q0.w);
        if (q1.x > V1) {                            // strict: q0 wins ties
            if (q1.z > V1) { V2 = q1.z; I2 = __float_as_int(q1.w); }
            else           { V2 = V1;   I2 = I1; }
            V1 = q1.x; I1 = __float_as_int(q1.y);
        } else if (q1.x > V2) {
            V2 = q1.x; I2 = __float_as_int(q1.y);
        }
        float d   = expf(V2 - V1);                  // softmax denom cancels
        float inv = 1.0f / (1.0f + d);
        res[tid] = make_float4(inv, __int_as_float(I1), d * inv, __int_as_float(I2));
    }
    __syncthreads();

    // ---- composed coalesced store: 64 tokens x 64 experts = 1024 float4 ----
    float4* outb = (float4*)out + (size_t)blockIdx.x * (TPB * E_DIM / 4);
    #pragma unroll
    for (int pp = 0; pp < 2; ++pp) {
        int p = tid + pp * 512;                     // 0..1023
        int t = p >> 4, cc = p & 15;
        float4 rr = res[t];
        int ri1 = __float_as_int(rr.y), ri2 = __float_as_int(rr.w);
        int e = cc * 4;
        float4 o;
        o.x = (e + 0 == ri1) ? rr.x : (e + 0 == ri2) ? rr.z : 0.0f;
        o.y = (e + 1 == ri1) ? rr.x : (e + 1 == ri2) ? rr.z : 0.0f;
        o.z = (e + 2 == ri1) ? rr.x : (e + 2 == ri2) ? rr.z : 0.0f;
        o.w = (e + 3 == ri1) ? rr.x : (e + 3 == ri2) ? rr.z : 0.0f;
        outb[p] = o;
    }
}

extern "C" void kernel_launch(void* const* d_in, const int* in_sizes, int n_in,
                              void* d_out, int out_size, void* d_ws, size_t ws_size,
                              hipStream_t stream) {
    const float* x     = (const float*)d_in[0];
    const float* se    = (const float*)d_in[1];
    const float* W     = (const float*)d_in[2];
    const float* noise = (const float*)d_in[3];
    const int*   sidx  = (const int*)d_in[4];
    float* out = (float*)d_out;

    unsigned short* Wp   = (unsigned short*)d_ws;                 // 786432 B
    float*          tail = (float*)((char*)d_ws + WP_TOTAL);      // 256 B

    hipLaunchKernelGGL(prep_kernel, dim3(65), dim3(256), 0, stream, W, se, sidx, Wp, tail);
    hipLaunchKernelGGL(router_kernel, dim3(NBLOCKS), dim3(512), 0, stream,
                       x, (const unsigned char*)Wp, tail, noise, out);
}

// Round 7
// 220.602 us; speedup vs baseline: 1.2657x; 1.1429x over previous
//
#include <hip/hip_runtime.h>
#include <hip/hip_bf16.h>
#include <math.h>
#include <stdint.h>

// ScaleAdaptiveRouter on MI355X (gfx950) — Round 18
// T=16384, H=2048, E=64, K=2112, top-2.
//
// Delivery model from R12-R16: per-wave vmem concurrency degenerates to
// ~1 outstanding wave-instr in every structure tried (compiler sinks reg
// pipelines; glds+barrier serializes on the queue) -> step time ~= #loads
// x ~650cy, all pipes idle. R17 (asm-forced depth-4) core-dumped.
// R18 removes the need for deep pipelining: B STATIONARY IN LDS.
//   - K split 8 ways: grid = 8 kr x 32 token-groups; each block preloads
//     its 96KB B-slice once (12 glds/thread), then the K-loop has only
//     TWO A-loads per wave-step (direct to VGPR).
//   - 8 waves x 64 tokens; 32 steps/wave: 2 loads + split3 + 12 ds_read
//     + 24 MFMA (4 nt-slices x 6-term bf16x3 chain, R6-verified order).
//   - depth-2 pipeline via 3 rotated named sets + sched_barrier(0)
//     fences (no asm loads; waits stay use-driven -> pipelined).
//   - partial logits atomicAdd'd (fp32) into zeroed 4MB ws buffer;
//     stage-2 kernel adds tail+noise, top-2, softmax, writes out.
// Numerics: within-partial MFMA order preserved; K reassociates across
// 8 partials (~1e-6 logit perturbation) -> absmax moves slightly off
// 0.00390625.

#define H_DIM 2048
#define K_TOTAL 2112
#define E_DIM 64
#define SE_DIM 64
#define NSTEP 64                        // total K32 steps over H
#define NKR 8                           // K-split factor
#define KR_LEN 256                      // k per kr slice
#define KS_PER_KR 8                     // K32 steps per kr
#define TG_TOK 512                      // tokens per block
#define STEP_BYTES (12 * 1024)
#define WP_TOTAL (NSTEP * STEP_BYTES)   // 786432 B
#define BSLICE_BYTES (KS_PER_KR * STEP_BYTES)   // 98304 B = 96 KB
#define LOGITS_OFF (WP_TOTAL + 256)     // ws offset of logits buffer
#define LOGITS_BYTES (16384 * E_DIM * 4)        // 4 MB

typedef float  f32x4 __attribute__((ext_vector_type(4)));
typedef short  s16x8 __attribute__((ext_vector_type(8)));
typedef unsigned int u32x4 __attribute__((ext_vector_type(4)));

typedef uint32_t __attribute__((address_space(1))) gu32_t;
typedef uint32_t __attribute__((address_space(3))) lu32_t;
__device__ __forceinline__ void gload_lds16(const void* g, void* l) {
    __builtin_amdgcn_global_load_lds((const gu32_t*)g, (lu32_t*)l, 16, 0, 0);
}

__device__ __forceinline__ unsigned short bf16_rne(float f) {
    uint32_t u = __float_as_uint(f);
    return (unsigned short)((u + 0x7FFFu + ((u >> 16) & 1u)) >> 16);
}
__device__ __forceinline__ float bf16_f32(unsigned short h) {
    return __uint_as_float(((uint32_t)h) << 16);
}
__device__ __forceinline__ uint32_t bits_of_bf2(__hip_bfloat162 h) {
    uint32_t u; __builtin_memcpy(&u, &h, 4); return u;
}

// ---- prep: split W into 3 bf16 planes laid out as MFMA B-fragments ----
// B-frag (16x16x32): lane l -> n = l&15, k = (l>>4)*8 + j. Record (s,nt,p):
// 64 lanes x 8 bf16 = 1 KB; record index = s*12 + nt*3 + p.  [R6-verified]
// Linear record order is (kr,ks)-nested automatically (s = kr*8+ks).
__global__ void prep_kernel(const float* __restrict__ W,
                            const float* __restrict__ se,
                            const int* __restrict__ sidx,
                            unsigned short* __restrict__ Wp,
                            float* __restrict__ tail) {
    if (blockIdx.x == 64) {
        int e = threadIdx.x;
        if (e < 64) {
            const float* emb = se + (*sidx) * SE_DIM;
            float t = 0.f;
            for (int j = 0; j < SE_DIM; ++j)
                t = fmaf(emb[j], W[(size_t)e * K_TOTAL + H_DIM + j], t);
            tail[e] = t;
        }
        return;
    }
    int item = blockIdx.x * 256 + threadIdx.x;   // (s, nt, lane)
    int lane = item & 63;
    int nt   = (item >> 6) & 3;
    int s    = item >> 8;
    int e     = nt * 16 + (lane & 15);
    int kbase = s * 32 + (lane >> 4) * 8;
    const float* wr = W + (size_t)e * K_TOTAL + kbase;
    unsigned short p0[8], p1[8], p2[8];
    #pragma unroll
    for (int j = 0; j < 8; ++j) {
        float v = wr[j];
        unsigned short a0 = bf16_rne(v);
        float r1 = v - bf16_f32(a0);
        unsigned short a1 = bf16_rne(r1);
        float r2 = r1 - bf16_f32(a1);
        p0[j] = a0; p1[j] = a1; p2[j] = bf16_rne(r2);
    }
    size_t rec = (size_t)s * 12 + nt * 3;
    unsigned short* d0 = Wp + (rec + 0) * 512 + lane * 8;
    unsigned short* d1 = Wp + (rec + 1) * 512 + lane * 8;
    unsigned short* d2 = Wp + (rec + 2) * 512 + lane * 8;
    #pragma unroll
    for (int j = 0; j < 8; ++j) { d0[j] = p0[j]; d1[j] = p1[j]; d2[j] = p2[j]; }
}

// split 8 consecutive-k floats into 3 bf16 A-fragment planes (packed pairs)
__device__ __forceinline__ void split3(const float4 fa, const float4 fb,
                                       s16x8& P0, s16x8& P1, s16x8& P2) {
    float f[8] = {fa.x, fa.y, fa.z, fa.w, fb.x, fb.y, fb.z, fb.w};
    uint32_t d0[4], d1[4], d2[4];
    #pragma unroll
    for (int p = 0; p < 4; ++p) {
        float v0 = f[2 * p], v1 = f[2 * p + 1];
        uint32_t u0 = bits_of_bf2(__float22bfloat162_rn(make_float2(v0, v1)));
        float r0 = v0 - __uint_as_float(u0 << 16);
        float r1 = v1 - __uint_as_float(u0 & 0xffff0000u);
        uint32_t u1 = bits_of_bf2(__float22bfloat162_rn(make_float2(r0, r1)));
        float s0 = r0 - __uint_as_float(u1 << 16);
        float s1 = r1 - __uint_as_float(u1 & 0xffff0000u);
        uint32_t u2 = bits_of_bf2(__float22bfloat162_rn(make_float2(s0, s1)));
        d0[p] = u0; d1[p] = u1; d2[p] = u2;
    }
    u32x4 q0 = {d0[0], d0[1], d0[2], d0[3]};
    u32x4 q1 = {d1[0], d1[1], d1[2], d1[3]};
    u32x4 q2 = {d2[0], d2[1], d2[2], d2[3]};
    __builtin_memcpy(&P0, &q0, 16);
    __builtin_memcpy(&P1, &q1, 16);
    __builtin_memcpy(&P2, &q2, 16);
}

// ---- stage 1: K-split GEMM, B stationary in LDS, atomic partials ----
__launch_bounds__(512, 2)
__global__ void gemm_kernel(const float* __restrict__ x,
                            const unsigned char* __restrict__ Wp,
                            float* __restrict__ logits) {
    __shared__ __align__(16) unsigned char Bs[BSLICE_BYTES];   // 96 KB

    const int tid  = threadIdx.x;                    // 0..511
    const int lane = tid & 63;
    const int wave = __builtin_amdgcn_readfirstlane(tid >> 6);  // 0..7
    const int kr   = blockIdx.x >> 5;                // 0..7 K-range
    const int tg   = blockIdx.x & 31;                // 0..31 token group
    const int row  = lane & 15;
    const int quad = lane >> 4;
    const int c    = row;                            // expert col in 16-slice

    // ---- B preload: 96 KB once (12 glds/thread, lane-linear dst) ----
    {
        const unsigned char* bsrc = Wp + (size_t)kr * BSLICE_BYTES + tid * 16;
        #pragma unroll
        for (int i = 0; i < 12; ++i)
            gload_lds16(bsrc + i * 8192, &Bs[tid * 16 + i * 8192]);
        asm volatile("s_waitcnt vmcnt(0)" ::: "memory");
        __syncthreads();
    }

    // wave owns 64 tokens: 4 m-tiles of 16; flat step j = mtile*8 + ks
    const float* ap = x + (size_t)(tg * TG_TOK + wave * 64 + row) * H_DIM
                        + kr * KR_LEN + quad * 8;
    f32x4 acc0 = {0.f, 0.f, 0.f, 0.f}, acc1 = acc0, acc2 = acc0, acc3 = acc0;

    #define A_ADDR(J) (ap + (size_t)((J) >> 3) * (16 * H_DIM) + ((J) & 7) * 32)
    #define ISSUE(J, VA, VB) do {                                  \
        const float* _p = A_ADDR(J);                               \
        VA = *(const float4*)_p;                                   \
        VB = *(const float4*)(_p + 4);                             \
    } while (0)

    #define FLUSH(MT) do {                                                  \
        int tokb = tg * TG_TOK + wave * 64 + (MT) * 16 + quad * 4;          \
        float* lg = logits + (size_t)tokb * E_DIM + c;                      \
        _Pragma("unroll")                                                   \
        for (int r = 0; r < 4; ++r) {                                       \
            atomicAdd(lg + r * E_DIM +  0, acc0[r]);                        \
            atomicAdd(lg + r * E_DIM + 16, acc1[r]);                        \
            atomicAdd(lg + r * E_DIM + 32, acc2[r]);                        \
            atomicAdd(lg + r * E_DIM + 48, acc3[r]);                        \
        }                                                                   \
        f32x4 _z = {0.f, 0.f, 0.f, 0.f};                                    \
        acc0 = _z; acc1 = _z; acc2 = _z; acc3 = _z;                         \
    } while (0)

    // per-step compute: split3 + 4 nt-slices x (3 ds_read + 6-term chain)
    #define COMPUTE(J, VA, VB) do {                                         \
        s16x8 A0, A1, A2;                                                   \
        split3(VA, VB, A0, A1, A2);                                         \
        const unsigned char* _bb = &Bs[((J) & 7) * STEP_BYTES + lane * 16]; \
        {                                                                   \
            s16x8 B0 = *(const s16x8*)(_bb);                                \
            s16x8 B1 = *(const s16x8*)(_bb + 1024);                         \
            s16x8 B2 = *(const s16x8*)(_bb + 2048);                         \
            acc0 = __builtin_amdgcn_mfma_f32_16x16x32_bf16(A0, B0, acc0, 0, 0, 0); \
            acc0 = __builtin_amdgcn_mfma_f32_16x16x32_bf16(A0, B1, acc0, 0, 0, 0); \
            acc0 = __builtin_amdgcn_mfma_f32_16x16x32_bf16(A1, B0, acc0, 0, 0, 0); \
            acc0 = __builtin_amdgcn_mfma_f32_16x16x32_bf16(A0, B2, acc0, 0, 0, 0); \
            acc0 = __builtin_amdgcn_mfma_f32_16x16x32_bf16(A1, B1, acc0, 0, 0, 0); \
            acc0 = __builtin_amdgcn_mfma_f32_16x16x32_bf16(A2, B0, acc0, 0, 0, 0); \
        }                                                                   \
        {                                                                   \
            s16x8 B0 = *(const s16x8*)(_bb + 3072);                         \
            s16x8 B1 = *(const s16x8*)(_bb + 4096);                         \
            s16x8 B2 = *(const s16x8*)(_bb + 5120);                         \
            acc1 = __builtin_amdgcn_mfma_f32_16x16x32_bf16(A0, B0, acc1, 0, 0, 0); \
            acc1 = __builtin_amdgcn_mfma_f32_16x16x32_bf16(A0, B1, acc1, 0, 0, 0); \
            acc1 = __builtin_amdgcn_mfma_f32_16x16x32_bf16(A1, B0, acc1, 0, 0, 0); \
            acc1 = __builtin_amdgcn_mfma_f32_16x16x32_bf16(A0, B2, acc1, 0, 0, 0); \
            acc1 = __builtin_amdgcn_mfma_f32_16x16x32_bf16(A1, B1, acc1, 0, 0, 0); \
            acc1 = __builtin_amdgcn_mfma_f32_16x16x32_bf16(A2, B0, acc1, 0, 0, 0); \
        }                                                                   \
        {                                                                   \
            s16x8 B0 = *(const s16x8*)(_bb + 6144);                         \
            s16x8 B1 = *(const s16x8*)(_bb + 7168);                         \
            s16x8 B2 = *(const s16x8*)(_bb + 8192);                         \
            acc2 = __builtin_amdgcn_mfma_f32_16x16x32_bf16(A0, B0, acc2, 0, 0, 0); \
            acc2 = __builtin_amdgcn_mfma_f32_16x16x32_bf16(A0, B1, acc2, 0, 0, 0); \
            acc2 = __builtin_amdgcn_mfma_f32_16x16x32_bf16(A1, B0, acc2, 0, 0, 0); \
            acc2 = __builtin_amdgcn_mfma_f32_16x16x32_bf16(A0, B2, acc2, 0, 0, 0); \
            acc2 = __builtin_amdgcn_mfma_f32_16x16x32_bf16(A1, B1, acc2, 0, 0, 0); \
            acc2 = __builtin_amdgcn_mfma_f32_16x16x32_bf16(A2, B0, acc2, 0, 0, 0); \
        }                                                                   \
        {                                                                   \
            s16x8 B0 = *(const s16x8*)(_bb + 9216);                         \
            s16x8 B1 = *(const s16x8*)(_bb + 10240);                        \
            s16x8 B2 = *(const s16x8*)(_bb + 11264);                        \
            acc3 = __builtin_amdgcn_mfma_f32_16x16x32_bf16(A0, B0, acc3, 0, 0, 0); \
            acc3 = __builtin_amdgcn_mfma_f32_16x16x32_bf16(A0, B1, acc3, 0, 0, 0); \
            acc3 = __builtin_amdgcn_mfma_f32_16x16x32_bf16(A1, B0, acc3, 0, 0, 0); \
            acc3 = __builtin_amdgcn_mfma_f32_16x16x32_bf16(A0, B2, acc3, 0, 0, 0); \
            acc3 = __builtin_amdgcn_mfma_f32_16x16x32_bf16(A1, B1, acc3, 0, 0, 0); \
            acc3 = __builtin_amdgcn_mfma_f32_16x16x32_bf16(A2, B0, acc3, 0, 0, 0); \
        }                                                                   \
        if (((J) & 7) == 7) FLUSH((J) >> 3);                                \
    } while (0)

    // ---- K loop: 32 steps, depth-2 pipeline, 3 rotated named sets,
    //      sched_barrier(0) pins loads above the compute that follows ----
    float4 a0_, b0_, a1_, b1_, a2_, b2_;
    ISSUE(0, a0_, b0_);
    ISSUE(1, a1_, b1_);
    #pragma unroll 1
    for (int it = 0; it < 10; ++it) {
        const int j = it * 3;
        ISSUE(j + 2, a2_, b2_);
        __builtin_amdgcn_sched_barrier(0);
        COMPUTE(j, a0_, b0_);
        ISSUE(j + 3, a0_, b0_);
        __builtin_amdgcn_sched_barrier(0);
        COMPUTE(j + 1, a1_, b1_);
        ISSUE(j + 4, a1_, b1_);
        __builtin_amdgcn_sched_barrier(0);
        COMPUTE(j + 2, a2_, b2_);
    }
    // j=30 (in a0_), j=31 (in a1_) issued during it=9
    COMPUTE(30, a0_, b0_);
    COMPUTE(31, a1_, b1_);

    #undef COMPUTE
    #undef FLUSH
    #undef ISSUE
    #undef A_ADDR
}

// ---- stage 2: per-token reduce is already done (atomics); add tail +
//      noise, top-2, softmax-pair, compose dense one-hot output ----
__launch_bounds__(256, 4)
__global__ void finish_kernel(const float* __restrict__ logits,
                              const float* __restrict__ tail,
                              const float* __restrict__ noise,
                              float* __restrict__ out) {
    const int t = blockIdx.x * 256 + threadIdx.x;    // token 0..16383
    const float4* L4 = (const float4*)(logits + (size_t)t * E_DIM);
    const float4* N4 = (const float4*)(noise  + (size_t)t * E_DIM);
    const float4* T4 = (const float4*)tail;

    float V1 = -3.4e38f, V2 = -3.4e38f;
    int   I1 = 0x7fffffff, I2 = 0x7fffffff;
    #define UPD(V, E) do {                                          \
        float _v = (V); int _e = (E);                               \
        if (_v > V1)      { V2 = V1; I2 = I1; V1 = _v; I1 = _e; }   \
        else if (_v > V2) { V2 = _v; I2 = _e; }                     \
    } while (0)
    #pragma unroll
    for (int i = 0; i < 16; ++i) {
        float4 l = L4[i], n = N4[i], tl = T4[i];
        UPD(l.x + tl.x + 0.1f * n.x, i * 4 + 0);
        UPD(l.y + tl.y + 0.1f * n.y, i * 4 + 1);
        UPD(l.z + tl.z + 0.1f * n.z, i * 4 + 2);
        UPD(l.w + tl.w + 0.1f * n.w, i * 4 + 3);
    }
    #undef UPD
    float d   = expf(V2 - V1);                  // softmax denom cancels
    float inv = 1.0f / (1.0f + d);
    float w1 = inv, w2 = d * inv;

    float4* O4 = (float4*)(out + (size_t)t * E_DIM);
    #pragma unroll
    for (int i = 0; i < 16; ++i) {
        int e = i * 4;
        float4 o;
        o.x = (e + 0 == I1) ? w1 : (e + 0 == I2) ? w2 : 0.0f;
        o.y = (e + 1 == I1) ? w1 : (e + 1 == I2) ? w2 : 0.0f;
        o.z = (e + 2 == I1) ? w1 : (e + 2 == I2) ? w2 : 0.0f;
        o.w = (e + 3 == I1) ? w1 : (e + 3 == I2) ? w2 : 0.0f;
        O4[i] = o;
    }
}

extern "C" void kernel_launch(void* const* d_in, const int* in_sizes, int n_in,
                              void* d_out, int out_size, void* d_ws, size_t ws_size,
                              hipStream_t stream) {
    const float* x     = (const float*)d_in[0];
    const float* se    = (const float*)d_in[1];
    const float* W     = (const float*)d_in[2];
    const float* noise = (const float*)d_in[3];
    const int*   sidx  = (const int*)d_in[4];
    float* out = (float*)d_out;

    unsigned short* Wp     = (unsigned short*)d_ws;                   // 786432 B
    float*          tail   = (float*)((char*)d_ws + WP_TOTAL);        // 256 B
    float*          logits = (float*)((char*)d_ws + LOGITS_OFF);      // 4 MB

    hipMemsetAsync(logits, 0, LOGITS_BYTES, stream);
    hipLaunchKernelGGL(prep_kernel, dim3(65), dim3(256), 0, stream,
                       W, se, sidx, Wp, tail);
    hipLaunchKernelGGL(gemm_kernel, dim3(NKR * 32), dim3(512), 0, stream,
                       x, (const unsigned char*)Wp, logits);
    hipLaunchKernelGGL(finish_kernel, dim3(64), dim3(256), 0, stream,
                       logits, tail, noise, out);
}